// Round 5
// baseline (202.904 us; speedup 1.0000x reference)
//
#include <hip/hip_runtime.h>

#define NEG_SLOPE 0.2f
#define LRELU(x) ((x) > 0.0f ? (x) : NEG_SLOPE * (x))

typedef short short8 __attribute__((ext_vector_type(8)));
typedef float f32x4v __attribute__((ext_vector_type(4)));

__device__ __forceinline__ unsigned short f2bf(float f) {
  unsigned int u = __float_as_uint(f);
  unsigned int r = (u + 0x7FFFu + ((u >> 16) & 1u)) >> 16;
  return (unsigned short)r;
}

__device__ __forceinline__ float bf2f(unsigned short u) {
  return __uint_as_float(((unsigned int)u) << 16);
}

__device__ __forceinline__ unsigned int cvt_pk_bf16(float lo, float hi) {
  unsigned int r;
  asm("v_cvt_pk_bf16_f32 %0, %1, %2" : "=v"(r) : "v"(lo), "v"(hi));
  return r;
}

__device__ __forceinline__ void gload_lds16(const void* g, void* l) {
  __builtin_amdgcn_global_load_lds(
      (const __attribute__((address_space(1))) unsigned int*)g,
      (__attribute__((address_space(3))) unsigned int*)l, 16, 0, 0);
}

// ------------- convert W (f32, [K=256][256]) -> Wt bf16 ([n][k]) -------------
__global__ __launch_bounds__(256) void convert_wt(const float* __restrict__ W,
                                                  unsigned short* __restrict__ Wtb) {
  int k = threadIdx.x;
  int n = blockIdx.x;
  Wtb[n * 256 + k] = f2bf(W[k * 256 + n]);
}

// ---------------- MFMA GEMM + fused attention dots ---------------------------
// A staged as f32 (direct from input X), converted to bf16 at fragment read via
// v_cvt_pk_bf16_f32 (RNE — identical numerics to the old convert_x pass).
// XHb[Mp,256](bf16) = bf16(X) @ W ; a_src/a_dst from f32 accumulators.
// 128x128 tile, BK=32, 4 waves, each wave 64x64 via 4x4 mfma_f32_16x16x32_bf16.
// grid = (2, Mp/128): N-block fastest -> consecutive blocks share A rows (L2).
__global__ __launch_bounds__(256) void gemm_mfma(
    const float* __restrict__ Xf, const unsigned short* __restrict__ Wtb,
    const float* __restrict__ attS, const float* __restrict__ attD,
    unsigned short* __restrict__ XHb, float* __restrict__ a_src,
    float* __restrict__ a_dst, int Mp, int N) {
  __shared__ float lAf[128 * 32];          // A tile, f32 [row][k]
  __shared__ unsigned short lB[128 * 32];  // B tile, bf16 [n][k]
  const int tid = threadIdx.x;
  const int lane = tid & 63;
  const int wave = tid >> 6;
  const int n0 = blockIdx.x * 128;
  const int m0 = blockIdx.y * 128;
  const int wr = (wave >> 1) * 64;
  const int wc = (wave & 1) * 64;

  f32x4v acc[4][4];
#pragma unroll
  for (int i = 0; i < 4; ++i)
#pragma unroll
    for (int j = 0; j < 4; ++j) acc[i][j] = (f32x4v)(0.0f);

  // A staging: 4 issues x 4KB; issue i covers rows [32i,32i+32), thread t ->
  // row 32i + (t>>3), byte (t&7)*16 within the 128B k-chunk of that row.
  const int rA = tid >> 3;
  const int kbA = (tid & 7) * 16;
  // B staging: 2 issues x 4KB; issue covers 64 rows (64B bf16 k-chunk/row).
  const int rB = tid >> 2;
  const int kbB = (tid & 3) * 16;

  const char* XfC = (const char*)Xf;
  const char* WtC = (const char*)Wtb;
  char* lAc = (char*)&lAf[0];
  char* lBc = (char*)&lB[0];
  const int ldsW = wave * 1024;
  const int lr = lane & 15;
  const int hq = lane >> 4;

  for (int k0 = 0; k0 < 256; k0 += 32) {
    // A: f32, row stride 1024B, k-offset k0*4
#pragma unroll
    for (int i = 0; i < 4; ++i) {
      int grow = m0 + i * 32 + rA;
      grow = min(grow, N - 1);  // clamp OOB rows (outputs discarded)
      gload_lds16(XfC + (size_t)grow * 1024 + (size_t)k0 * 4 + kbA,
                  lAc + i * 4096 + ldsW);
    }
    // B: bf16, row stride 512B, k-offset k0*2
    gload_lds16(WtC + (size_t)(n0 + rB) * 512 + (size_t)k0 * 2 + kbB, lBc + ldsW);
    gload_lds16(WtC + (size_t)(n0 + rB + 64) * 512 + (size_t)k0 * 2 + kbB,
                lBc + ldsW + 4096);
    __syncthreads();

    short8 a[4], b[4];
#pragma unroll
    for (int i = 0; i < 4; ++i) {
      int ar = wr + i * 16 + lr;
      float4 f0 = *reinterpret_cast<const float4*>(&lAf[ar * 32 + hq * 8]);
      float4 f1 = *reinterpret_cast<const float4*>(&lAf[ar * 32 + hq * 8 + 4]);
      union { unsigned int u[4]; short8 s; } ua;
      ua.u[0] = cvt_pk_bf16(f0.x, f0.y);
      ua.u[1] = cvt_pk_bf16(f0.z, f0.w);
      ua.u[2] = cvt_pk_bf16(f1.x, f1.y);
      ua.u[3] = cvt_pk_bf16(f1.z, f1.w);
      a[i] = ua.s;
    }
#pragma unroll
    for (int j = 0; j < 4; ++j)
      b[j] = *reinterpret_cast<const short8*>(lBc + (wc + j * 16 + lr) * 64 + hq * 16);
#pragma unroll
    for (int i = 0; i < 4; ++i)
#pragma unroll
      for (int j = 0; j < 4; ++j)
        acc[i][j] = __builtin_amdgcn_mfma_f32_16x16x32_bf16(a[i], b[j], acc[i][j], 0, 0, 0);
    __syncthreads();
  }

  // ---- epilogue ----
  const int h = (n0 + wc) >> 6;  // this wave's head (64-aligned col span)
  float ws_[4], wd_[4];
#pragma unroll
  for (int j = 0; j < 4; ++j) {
    ws_[j] = attS[h * 64 + j * 16 + lr];
    wd_[j] = attD[h * 64 + j * 16 + lr];
  }
  const int rbase = m0 + wr + hq * 4;

#pragma unroll
  for (int i = 0; i < 4; ++i) {
#pragma unroll
    for (int r = 0; r < 4; ++r) {
      float ps = 0.f, pd = 0.f;
#pragma unroll
      for (int j = 0; j < 4; ++j) {
        ps += acc[i][j][r] * ws_[j];
        pd += acc[i][j][r] * wd_[j];
      }
#pragma unroll
      for (int off = 1; off < 16; off <<= 1) {
        ps += __shfl_xor(ps, off, 64);
        pd += __shfl_xor(pd, off, 64);
      }
      int row = rbase + i * 16 + r;
      if (lr == 0 && row < N) {
        a_src[row * 4 + h] = ps;
        a_dst[row * 4 + h] = pd;
      }
    }
  }

#pragma unroll
  for (int i = 0; i < 4; ++i)
#pragma unroll
    for (int j = 0; j < 4; ++j) {
      int col = n0 + wc + j * 16 + lr;
#pragma unroll
      for (int r = 0; r < 4; ++r)
        XHb[(size_t)(rbase + i * 16 + r) * 256 + col] = f2bf(acc[i][j][r]);
    }
}

// ------------------------------- CSR build -----------------------------------
__global__ void count_kernel(const int* __restrict__ ei, int* __restrict__ deg, int E) {
  int e = blockIdx.x * blockDim.x + threadIdx.x;
  if (e < E) atomicAdd(&deg[ei[E + e]], 1);
}

__global__ __launch_bounds__(1024) void scan1_kernel(const int* __restrict__ deg,
                                                     int* __restrict__ row_start,
                                                     int* __restrict__ bsum, int N) {
  __shared__ int buf[1024];
  int i = blockIdx.x * 1024 + (int)threadIdx.x;
  int v = (i < N) ? deg[i] : 0;
  buf[threadIdx.x] = v;
  __syncthreads();
  int run = v;
  for (int off = 1; off < 1024; off <<= 1) {
    int t = ((int)threadIdx.x >= off) ? buf[threadIdx.x - off] : 0;
    __syncthreads();
    run += t;
    buf[threadIdx.x] = run;
    __syncthreads();
  }
  if (i < N) row_start[i] = run - v;  // exclusive, pre-block-offset
  if (threadIdx.x == 1023) bsum[blockIdx.x] = run;
}

__global__ void scan2_kernel(int* __restrict__ bsum, int* __restrict__ row_start,
                             int nb, int N) {
  int acc = 0;
  for (int b = 0; b < nb; ++b) {
    int t = bsum[b];
    bsum[b] = acc;
    acc += t;
  }
  row_start[N] = acc;
}

__global__ __launch_bounds__(1024) void scan3_kernel(int* __restrict__ row_start,
                                                     const int* __restrict__ bsum, int N) {
  int i = blockIdx.x * 1024 + (int)threadIdx.x;
  if (i < N) row_start[i] += bsum[blockIdx.x];
}

__global__ void fill_kernel(const int* __restrict__ ei, const int* __restrict__ row_start,
                            int* __restrict__ cursor, int* __restrict__ csr_src, int E) {
  int e = blockIdx.x * blockDim.x + threadIdx.x;
  if (e < E) {
    int d = ei[E + e];
    int slot = row_start[d] + atomicAdd(&cursor[d], 1);
    csr_src[slot] = ei[e];
  }
}

// ---- fused softmax + aggregation, single pass (no max-shift) ----------------
// one wave per dst node; 8-deep unrolled gather pipeline.
__global__ __launch_bounds__(256) void gat_agg(
    const unsigned short* __restrict__ XHb, const float* __restrict__ a_src,
    const float* __restrict__ a_dst, const int* __restrict__ row_start,
    const int* __restrict__ csr_src, const float* __restrict__ bias,
    float* __restrict__ out, int N) {
  int wid = threadIdx.x >> 6;
  int lane = threadIdx.x & 63;
  int node = blockIdx.x * 4 + wid;
  if (node >= N) return;

  int h = lane >> 4;
  int c = lane << 2;
  const unsigned short* __restrict__ xrow = XHb + c;  // lane-fixed column base
  float ad_h = a_dst[node * 4 + h];
  float as_h = a_src[node * 4 + h];
  float wself = __expf(LRELU(as_h + ad_h));

  int start = row_start[node];
  int end = row_start[node + 1];

  ushort4 sv = *reinterpret_cast<const ushort4*>(xrow + (size_t)node * 256);
  float4 acc;
  acc.x = wself * bf2f(sv.x); acc.y = wself * bf2f(sv.y);
  acc.z = wself * bf2f(sv.z); acc.w = wself * bf2f(sv.w);
  float sw = wself;

  int p = start;
  for (; p + 8 <= end; p += 8) {
    int s0 = csr_src[p];
    int s1 = csr_src[p + 1];
    int s2 = csr_src[p + 2];
    int s3 = csr_src[p + 3];
    int s4 = csr_src[p + 4];
    int s5 = csr_src[p + 5];
    int s6 = csr_src[p + 6];
    int s7 = csr_src[p + 7];
    ushort4 u0 = *reinterpret_cast<const ushort4*>(xrow + (size_t)s0 * 256);
    ushort4 u1 = *reinterpret_cast<const ushort4*>(xrow + (size_t)s1 * 256);
    ushort4 u2 = *reinterpret_cast<const ushort4*>(xrow + (size_t)s2 * 256);
    ushort4 u3 = *reinterpret_cast<const ushort4*>(xrow + (size_t)s3 * 256);
    ushort4 u4 = *reinterpret_cast<const ushort4*>(xrow + (size_t)s4 * 256);
    ushort4 u5 = *reinterpret_cast<const ushort4*>(xrow + (size_t)s5 * 256);
    ushort4 u6 = *reinterpret_cast<const ushort4*>(xrow + (size_t)s6 * 256);
    ushort4 u7 = *reinterpret_cast<const ushort4*>(xrow + (size_t)s7 * 256);
    float a0 = a_src[s0 * 4 + h] + ad_h;
    float a1 = a_src[s1 * 4 + h] + ad_h;
    float a2 = a_src[s2 * 4 + h] + ad_h;
    float a3 = a_src[s3 * 4 + h] + ad_h;
    float a4 = a_src[s4 * 4 + h] + ad_h;
    float a5 = a_src[s5 * 4 + h] + ad_h;
    float a6 = a_src[s6 * 4 + h] + ad_h;
    float a7 = a_src[s7 * 4 + h] + ad_h;
    float w0 = __expf(LRELU(a0));
    float w1 = __expf(LRELU(a1));
    float w2 = __expf(LRELU(a2));
    float w3 = __expf(LRELU(a3));
    float w4 = __expf(LRELU(a4));
    float w5 = __expf(LRELU(a5));
    float w6 = __expf(LRELU(a6));
    float w7 = __expf(LRELU(a7));
    acc.x += w0 * bf2f(u0.x); acc.y += w0 * bf2f(u0.y);
    acc.z += w0 * bf2f(u0.z); acc.w += w0 * bf2f(u0.w);
    acc.x += w1 * bf2f(u1.x); acc.y += w1 * bf2f(u1.y);
    acc.z += w1 * bf2f(u1.z); acc.w += w1 * bf2f(u1.w);
    acc.x += w2 * bf2f(u2.x); acc.y += w2 * bf2f(u2.y);
    acc.z += w2 * bf2f(u2.z); acc.w += w2 * bf2f(u2.w);
    acc.x += w3 * bf2f(u3.x); acc.y += w3 * bf2f(u3.y);
    acc.z += w3 * bf2f(u3.z); acc.w += w3 * bf2f(u3.w);
    acc.x += w4 * bf2f(u4.x); acc.y += w4 * bf2f(u4.y);
    acc.z += w4 * bf2f(u4.z); acc.w += w4 * bf2f(u4.w);
    acc.x += w5 * bf2f(u5.x); acc.y += w5 * bf2f(u5.y);
    acc.z += w5 * bf2f(u5.z); acc.w += w5 * bf2f(u5.w);
    acc.x += w6 * bf2f(u6.x); acc.y += w6 * bf2f(u6.y);
    acc.z += w6 * bf2f(u6.z); acc.w += w6 * bf2f(u6.w);
    acc.x += w7 * bf2f(u7.x); acc.y += w7 * bf2f(u7.y);
    acc.z += w7 * bf2f(u7.z); acc.w += w7 * bf2f(u7.w);
    sw += ((w0 + w1) + (w2 + w3)) + ((w4 + w5) + (w6 + w7));
  }
  for (; p < end; ++p) {
    int s0 = csr_src[p];
    float a0 = a_src[s0 * 4 + h] + ad_h;
    ushort4 u0 = *reinterpret_cast<const ushort4*>(xrow + (size_t)s0 * 256);
    float w0 = __expf(LRELU(a0));
    acc.x += w0 * bf2f(u0.x); acc.y += w0 * bf2f(u0.y);
    acc.z += w0 * bf2f(u0.z); acc.w += w0 * bf2f(u0.w);
    sw += w0;
  }

  float inv = 1.0f / sw;
  float4 b = reinterpret_cast<const float4*>(bias)[lane];
  float4 o;
  o.x = acc.x * inv + b.x; o.y = acc.y * inv + b.y;
  o.z = acc.z * inv + b.z; o.w = acc.w * inv + b.w;
  *reinterpret_cast<float4*>(out + (size_t)node * 256 + c) = o;
}

extern "C" void kernel_launch(void* const* d_in, const int* in_sizes, int n_in,
                              void* d_out, int out_size, void* d_ws, size_t ws_size,
                              hipStream_t stream) {
  const float* x    = (const float*)d_in[0];
  const int*   ei   = (const int*)d_in[1];
  const float* Wm   = (const float*)d_in[2];
  const float* attS = (const float*)d_in[3];
  const float* attD = (const float*)d_in[4];
  const float* bias = (const float*)d_in[5];
  float* out = (float*)d_out;

  const int N = in_sizes[0] / 256;
  const int E = in_sizes[1] / 2;
  const int Mp = (N + 127) / 128 * 128;
  const int nb = (N + 1023) / 1024;

  char* w = (char*)d_ws;
  unsigned short* XHb = (unsigned short*)w;  w += (size_t)Mp * 256 * 2;
  unsigned short* Wtb = (unsigned short*)w;  w += (size_t)256 * 256 * 2;
  float* a_src = (float*)w;                  w += (size_t)N * 4 * 4;
  float* a_dst = (float*)w;                  w += (size_t)N * 4 * 4;
  int* deg = (int*)w;                        w += (size_t)N * 4;
  int* cursor = (int*)w;                     w += (size_t)N * 4;
  int* row_start = (int*)w;                  w += ((size_t)(N + 1) * 4 + 255) / 256 * 256;
  int* bsum = (int*)w;                       w += ((size_t)nb * 4 + 255) / 256 * 256;
  int* csr_src = (int*)w;                    w += (size_t)E * 4;

  convert_wt<<<256, 256, 0, stream>>>(Wm, Wtb);

  // MFMA GEMM (A = f32 input, converted in-kernel); N-block fastest for L2 reuse
  dim3 ggrid(2, Mp / 128);
  gemm_mfma<<<ggrid, 256, 0, stream>>>(x, Wtb, attS, attD, XHb, a_src, a_dst, Mp, N);

  hipMemsetAsync(deg, 0, (size_t)2 * N * 4, stream);  // deg + cursor (adjacent)
  count_kernel<<<(E + 255) / 256, 256, 0, stream>>>(ei, deg, E);
  scan1_kernel<<<nb, 1024, 0, stream>>>(deg, row_start, bsum, N);
  scan2_kernel<<<1, 1, 0, stream>>>(bsum, row_start, nb, N);
  scan3_kernel<<<nb, 1024, 0, stream>>>(row_start, bsum, N);
  fill_kernel<<<(E + 255) / 256, 256, 0, stream>>>(ei, row_start, cursor, csr_src, E);

  gat_agg<<<(N + 3) / 4, 256, 0, stream>>>(XHb, a_src, a_dst, row_start, csr_src,
                                           bias, out, N);
}

// Round 6
// 175.259 us; speedup vs baseline: 1.1577x; 1.1577x over previous
//
#include <hip/hip_runtime.h>

#define NEG_SLOPE 0.2f
#define LRELU(x) ((x) > 0.0f ? (x) : NEG_SLOPE * (x))

typedef short short8 __attribute__((ext_vector_type(8)));
typedef float f32x4v __attribute__((ext_vector_type(4)));

__device__ __forceinline__ unsigned short f2bf(float f) {
  unsigned int u = __float_as_uint(f);
  unsigned int r = (u + 0x7FFFu + ((u >> 16) & 1u)) >> 16;
  return (unsigned short)r;
}

__device__ __forceinline__ float bf2f(unsigned short u) {
  return __uint_as_float(((unsigned int)u) << 16);
}

__device__ __forceinline__ void gload_lds16(const void* g, void* l) {
  __builtin_amdgcn_global_load_lds(
      (const __attribute__((address_space(1))) unsigned int*)g,
      (__attribute__((address_space(3))) unsigned int*)l, 16, 0, 0);
}

// block-range split constants for fused kernels
#define CBX 1536  // convert_x blocks
#define CBC 512   // count blocks
#define CBW 64    // convert_wt blocks
#define CBF 512   // fill blocks

// ---- K1: convert_x || convert_wt || count (independent, fused) --------------
__global__ __launch_bounds__(256) void fused_pre(
    const float* __restrict__ X, unsigned short* __restrict__ Xb,
    const float* __restrict__ W, unsigned short* __restrict__ Wtb,
    const int* __restrict__ ei, int* __restrict__ deg,
    int totalX, int validX, int E) {
  int b = blockIdx.x;
  int tid = threadIdx.x;
  if (b < CBX) {
    // convert x -> bf16, zero-pad rows to Mp
    for (int i = (b * 256 + tid) * 4; i < totalX; i += CBX * 256 * 4) {
      ushort4 o;
      if (i < validX) {
        float4 v = *reinterpret_cast<const float4*>(X + i);
        o.x = f2bf(v.x); o.y = f2bf(v.y); o.z = f2bf(v.z); o.w = f2bf(v.w);
      } else {
        o.x = o.y = o.z = o.w = 0;
      }
      *reinterpret_cast<ushort4*>(Xb + i) = o;
    }
  } else if (b < CBX + CBC) {
    // degree count
    int bb = b - CBX;
    for (int e = bb * 256 + tid; e < E; e += CBC * 256)
      atomicAdd(&deg[ei[E + e]], 1);
  } else {
    // W[K][256] -> Wt bf16 [n][k]
    int bb = b - CBX - CBC;
    for (int idx = bb * 256 + tid; idx < 256 * 256; idx += CBW * 256) {
      int n = idx >> 8, k = idx & 255;
      Wtb[n * 256 + k] = f2bf(W[k * 256 + n]);
    }
  }
}

// ------------------------------- scan ----------------------------------------
__global__ __launch_bounds__(1024) void scan1_kernel(const int* __restrict__ deg,
                                                     int* __restrict__ row_start,
                                                     int* __restrict__ bsum, int N) {
  __shared__ int buf[1024];
  int i = blockIdx.x * 1024 + (int)threadIdx.x;
  int v = (i < N) ? deg[i] : 0;
  buf[threadIdx.x] = v;
  __syncthreads();
  int run = v;
  for (int off = 1; off < 1024; off <<= 1) {
    int t = ((int)threadIdx.x >= off) ? buf[threadIdx.x - off] : 0;
    __syncthreads();
    run += t;
    buf[threadIdx.x] = run;
    __syncthreads();
  }
  if (i < N) row_start[i] = run - v;  // exclusive, pre-block-offset
  if (threadIdx.x == 1023) bsum[blockIdx.x] = run;
}

// each block wave-reduces its bsum prefix (nb <= ~64, trivial) then offsets
__global__ __launch_bounds__(1024) void scan_off(int* __restrict__ row_start,
                                                 const int* __restrict__ bsum,
                                                 int nb, int N) {
  __shared__ int s_off;
  int b = blockIdx.x;
  if (threadIdx.x < 64) {
    int acc = 0;
    for (int j = (int)threadIdx.x; j < b; j += 64) acc += bsum[j];
    for (int off = 32; off; off >>= 1) acc += __shfl_down(acc, off, 64);
    if (threadIdx.x == 0) s_off = acc;
  }
  __syncthreads();
  int off = s_off;
  int i = b * 1024 + (int)threadIdx.x;
  if (i < N) row_start[i] += off;
  if (b == nb - 1 && threadIdx.x == 0) row_start[N] = off + bsum[b];
}

// ---- K4: MFMA GEMM (+fused att dots) || CSR fill ----------------------------
// gemm: 128x128 tile, BK=32, 4 waves, 4x4 mfma_f32_16x16x32_bf16; bf16 staging.
// blocks [0,nGemm): gemm (n-block fastest -> A-tile L2 reuse); rest: fill.
__global__ __launch_bounds__(256) void fused_main(
    const unsigned short* __restrict__ Xb, const unsigned short* __restrict__ Wtb,
    const float* __restrict__ attS, const float* __restrict__ attD,
    unsigned short* __restrict__ XHb, float* __restrict__ a_src,
    float* __restrict__ a_dst,
    const int* __restrict__ ei, const int* __restrict__ row_start,
    int* __restrict__ cursor, int* __restrict__ csr_src,
    int nGemm, int E, int N) {
  __shared__ unsigned short lA[128 * 32];
  __shared__ unsigned short lB[128 * 32];
  const int bid = blockIdx.x;
  const int tid = threadIdx.x;

  if (bid >= nGemm) {
    // ---------------- fill ----------------
    int bb = bid - nGemm;
    for (int e = bb * 256 + tid; e < E; e += CBF * 256) {
      int d = ei[E + e];
      int slot = row_start[d] + atomicAdd(&cursor[d], 1);
      csr_src[slot] = ei[e];
    }
    return;
  }

  // ---------------- gemm ----------------
  const int lane = tid & 63;
  const int wave = tid >> 6;
  const int n0 = (bid & 1) * 128;
  const int m0 = (bid >> 1) * 128;
  const int wr = (wave >> 1) * 64;
  const int wc = (wave & 1) * 64;

  f32x4v acc[4][4];
#pragma unroll
  for (int i = 0; i < 4; ++i)
#pragma unroll
    for (int j = 0; j < 4; ++j) acc[i][j] = (f32x4v)(0.0f);

  const int srow = tid >> 2;
  const int skb = (tid & 3) * 16;
  const char* XbC = (const char*)Xb;
  const char* WtC = (const char*)Wtb;
  char* lAc = (char*)&lA[0];
  char* lBc = (char*)&lB[0];
  const int ldsB0 = wave * 1024;
  const int lr = lane & 15;
  const int hq = lane >> 4;
  const int kq = hq * 16;

  for (int k0 = 0; k0 < 256; k0 += 32) {
    const size_t kbyte = (size_t)k0 * 2 + skb;
    gload_lds16(XbC + (size_t)(m0 + srow) * 512 + kbyte, lAc + ldsB0);
    gload_lds16(XbC + (size_t)(m0 + srow + 64) * 512 + kbyte, lAc + ldsB0 + 4096);
    gload_lds16(WtC + (size_t)(n0 + srow) * 512 + kbyte, lBc + ldsB0);
    gload_lds16(WtC + (size_t)(n0 + srow + 64) * 512 + kbyte, lBc + ldsB0 + 4096);
    __syncthreads();

    short8 a[4], b[4];
#pragma unroll
    for (int i = 0; i < 4; ++i)
      a[i] = *reinterpret_cast<const short8*>(lAc + (wr + i * 16 + lr) * 64 + kq);
#pragma unroll
    for (int j = 0; j < 4; ++j)
      b[j] = *reinterpret_cast<const short8*>(lBc + (wc + j * 16 + lr) * 64 + kq);
#pragma unroll
    for (int i = 0; i < 4; ++i)
#pragma unroll
      for (int j = 0; j < 4; ++j)
        acc[i][j] = __builtin_amdgcn_mfma_f32_16x16x32_bf16(a[i], b[j], acc[i][j], 0, 0, 0);
    __syncthreads();
  }

  // ---- epilogue: fused attention dots + bf16 store ----
  const int h = (n0 + wc) >> 6;
  float ws_[4], wd_[4];
#pragma unroll
  for (int j = 0; j < 4; ++j) {
    ws_[j] = attS[h * 64 + j * 16 + lr];
    wd_[j] = attD[h * 64 + j * 16 + lr];
  }
  const int rbase = m0 + wr + hq * 4;

#pragma unroll
  for (int i = 0; i < 4; ++i) {
#pragma unroll
    for (int r = 0; r < 4; ++r) {
      float ps = 0.f, pd = 0.f;
#pragma unroll
      for (int j = 0; j < 4; ++j) {
        ps += acc[i][j][r] * ws_[j];
        pd += acc[i][j][r] * wd_[j];
      }
#pragma unroll
      for (int off = 1; off < 16; off <<= 1) {
        ps += __shfl_xor(ps, off, 64);
        pd += __shfl_xor(pd, off, 64);
      }
      int row = rbase + i * 16 + r;
      if (lr == 0 && row < N) {
        a_src[row * 4 + h] = ps;
        a_dst[row * 4 + h] = pd;
      }
    }
  }

#pragma unroll
  for (int i = 0; i < 4; ++i)
#pragma unroll
    for (int j = 0; j < 4; ++j) {
      int col = n0 + wc + j * 16 + lr;
#pragma unroll
      for (int r = 0; r < 4; ++r)
        XHb[(size_t)(rbase + i * 16 + r) * 256 + col] = f2bf(acc[i][j][r]);
    }
}

// ---- fused softmax + aggregation, single pass (no max-shift) ----------------
// one wave per dst node; 4-deep unrolled gather pipeline (R4-best: VGPR 24).
__global__ __launch_bounds__(256) void gat_agg(
    const unsigned short* __restrict__ XHb, const float* __restrict__ a_src,
    const float* __restrict__ a_dst, const int* __restrict__ row_start,
    const int* __restrict__ csr_src, const float* __restrict__ bias,
    float* __restrict__ out, int N) {
  int wid = threadIdx.x >> 6;
  int lane = threadIdx.x & 63;
  int node = blockIdx.x * 4 + wid;
  if (node >= N) return;

  int h = lane >> 4;
  int c = lane << 2;
  const unsigned short* __restrict__ xrow = XHb + c;
  float ad_h = a_dst[node * 4 + h];
  float as_h = a_src[node * 4 + h];
  float wself = __expf(LRELU(as_h + ad_h));

  int start = row_start[node];
  int end = row_start[node + 1];

  ushort4 sv = *reinterpret_cast<const ushort4*>(xrow + (size_t)node * 256);
  float4 acc;
  acc.x = wself * bf2f(sv.x); acc.y = wself * bf2f(sv.y);
  acc.z = wself * bf2f(sv.z); acc.w = wself * bf2f(sv.w);
  float sw = wself;

  int p = start;
  for (; p + 4 <= end; p += 4) {
    int s0 = csr_src[p];
    int s1 = csr_src[p + 1];
    int s2 = csr_src[p + 2];
    int s3 = csr_src[p + 3];
    float a0 = a_src[s0 * 4 + h] + ad_h;
    float a1 = a_src[s1 * 4 + h] + ad_h;
    float a2 = a_src[s2 * 4 + h] + ad_h;
    float a3 = a_src[s3 * 4 + h] + ad_h;
    ushort4 u0 = *reinterpret_cast<const ushort4*>(xrow + (size_t)s0 * 256);
    ushort4 u1 = *reinterpret_cast<const ushort4*>(xrow + (size_t)s1 * 256);
    ushort4 u2 = *reinterpret_cast<const ushort4*>(xrow + (size_t)s2 * 256);
    ushort4 u3 = *reinterpret_cast<const ushort4*>(xrow + (size_t)s3 * 256);
    float w0 = __expf(LRELU(a0));
    float w1 = __expf(LRELU(a1));
    float w2 = __expf(LRELU(a2));
    float w3 = __expf(LRELU(a3));
    acc.x += w0 * bf2f(u0.x); acc.y += w0 * bf2f(u0.y);
    acc.z += w0 * bf2f(u0.z); acc.w += w0 * bf2f(u0.w);
    acc.x += w1 * bf2f(u1.x); acc.y += w1 * bf2f(u1.y);
    acc.z += w1 * bf2f(u1.z); acc.w += w1 * bf2f(u1.w);
    acc.x += w2 * bf2f(u2.x); acc.y += w2 * bf2f(u2.y);
    acc.z += w2 * bf2f(u2.z); acc.w += w2 * bf2f(u2.w);
    acc.x += w3 * bf2f(u3.x); acc.y += w3 * bf2f(u3.y);
    acc.z += w3 * bf2f(u3.z); acc.w += w3 * bf2f(u3.w);
    sw += (w0 + w1) + (w2 + w3);
  }
  for (; p < end; ++p) {
    int s0 = csr_src[p];
    float a0 = a_src[s0 * 4 + h] + ad_h;
    ushort4 u0 = *reinterpret_cast<const ushort4*>(xrow + (size_t)s0 * 256);
    float w0 = __expf(LRELU(a0));
    acc.x += w0 * bf2f(u0.x); acc.y += w0 * bf2f(u0.y);
    acc.z += w0 * bf2f(u0.z); acc.w += w0 * bf2f(u0.w);
    sw += w0;
  }

  float inv = 1.0f / sw;
  float4 b = reinterpret_cast<const float4*>(bias)[lane];
  float4 o;
  o.x = acc.x * inv + b.x; o.y = acc.y * inv + b.y;
  o.z = acc.z * inv + b.z; o.w = acc.w * inv + b.w;
  *reinterpret_cast<float4*>(out + (size_t)node * 256 + c) = o;
}

extern "C" void kernel_launch(void* const* d_in, const int* in_sizes, int n_in,
                              void* d_out, int out_size, void* d_ws, size_t ws_size,
                              hipStream_t stream) {
  const float* x    = (const float*)d_in[0];
  const int*   ei   = (const int*)d_in[1];
  const float* Wm   = (const float*)d_in[2];
  const float* attS = (const float*)d_in[3];
  const float* attD = (const float*)d_in[4];
  const float* bias = (const float*)d_in[5];
  float* out = (float*)d_out;

  const int N = in_sizes[0] / 256;
  const int E = in_sizes[1] / 2;
  const int Mp = (N + 127) / 128 * 128;
  const int nb = (N + 1023) / 1024;

  char* w = (char*)d_ws;
  unsigned short* XHb = (unsigned short*)w;  w += (size_t)Mp * 256 * 2;
  unsigned short* Xb  = (unsigned short*)w;  w += (size_t)Mp * 256 * 2;
  unsigned short* Wtb = (unsigned short*)w;  w += (size_t)256 * 256 * 2;
  float* a_src = (float*)w;                  w += (size_t)N * 4 * 4;
  float* a_dst = (float*)w;                  w += (size_t)N * 4 * 4;
  int* deg = (int*)w;                        w += (size_t)N * 4;
  int* cursor = (int*)w;                     w += (size_t)N * 4;
  int* row_start = (int*)w;                  w += ((size_t)(N + 1) * 4 + 255) / 256 * 256;
  int* bsum = (int*)w;                       w += ((size_t)nb * 4 + 255) / 256 * 256;
  int* csr_src = (int*)w;                    w += (size_t)E * 4;

  // deg + cursor zero (adjacent)
  hipMemsetAsync(deg, 0, (size_t)2 * N * 4, stream);

  // K1: convert_x || convert_wt || count
  fused_pre<<<CBX + CBC + CBW, 256, 0, stream>>>(x, Xb, Wm, Wtb, ei, deg,
                                                 Mp * 256, N * 256, E);

  // scan (2 kernels)
  scan1_kernel<<<nb, 1024, 0, stream>>>(deg, row_start, bsum, N);
  scan_off<<<nb, 1024, 0, stream>>>(row_start, bsum, nb, N);

  // K4: gemm || fill
  const int nGemm = 2 * (Mp / 128);
  fused_main<<<nGemm + CBF, 256, 0, stream>>>(Xb, Wtb, attS, attD, XHb, a_src, a_dst,
                                              ei, row_start, cursor, csr_src,
                                              nGemm, E, N);

  // fused softmax + aggregate
  gat_agg<<<(N + 3) / 4, 256, 0, stream>>>(XHb, a_src, a_dst, row_start, csr_src,
                                           bias, out, N);
}

// Round 7
// 173.270 us; speedup vs baseline: 1.1710x; 1.0115x over previous
//
#include <hip/hip_runtime.h>

#define NEG_SLOPE 0.2f
#define LRELU(x) ((x) > 0.0f ? (x) : NEG_SLOPE * (x))

typedef short short8 __attribute__((ext_vector_type(8)));
typedef unsigned short ushort8 __attribute__((ext_vector_type(8)));
typedef float f32x4v __attribute__((ext_vector_type(4)));

__device__ __forceinline__ unsigned short f2bf(float f) {
  unsigned int u = __float_as_uint(f);
  unsigned int r = (u + 0x7FFFu + ((u >> 16) & 1u)) >> 16;
  return (unsigned short)r;
}

__device__ __forceinline__ float bf2f(unsigned short u) {
  return __uint_as_float(((unsigned int)u) << 16);
}

__device__ __forceinline__ void gload_lds16(const void* g, void* l) {
  __builtin_amdgcn_global_load_lds(
      (const __attribute__((address_space(1))) unsigned int*)g,
      (__attribute__((address_space(3))) unsigned int*)l, 16, 0, 0);
}

// block-range split constants for fused kernels
#define CBX 1536  // convert_x blocks
#define CBC 512   // count blocks
#define CBW 64    // convert_wt blocks
#define CBF 512   // fill blocks

// ---- K1: convert_x || convert_wt || count (independent, fused) --------------
__global__ __launch_bounds__(256) void fused_pre(
    const float* __restrict__ X, unsigned short* __restrict__ Xb,
    const float* __restrict__ W, unsigned short* __restrict__ Wtb,
    const int* __restrict__ ei, int* __restrict__ deg,
    int totalX, int validX, int E) {
  int b = blockIdx.x;
  int tid = threadIdx.x;
  if (b < CBX) {
    for (int i = (b * 256 + tid) * 4; i < totalX; i += CBX * 256 * 4) {
      ushort4 o;
      if (i < validX) {
        float4 v = *reinterpret_cast<const float4*>(X + i);
        o.x = f2bf(v.x); o.y = f2bf(v.y); o.z = f2bf(v.z); o.w = f2bf(v.w);
      } else {
        o.x = o.y = o.z = o.w = 0;
      }
      *reinterpret_cast<ushort4*>(Xb + i) = o;
    }
  } else if (b < CBX + CBC) {
    int bb = b - CBX;
    for (int e = bb * 256 + tid; e < E; e += CBC * 256)
      atomicAdd(&deg[ei[E + e]], 1);
  } else {
    int bb = b - CBX - CBC;
    for (int idx = bb * 256 + tid; idx < 256 * 256; idx += CBW * 256) {
      int n = idx >> 8, k = idx & 255;
      Wtb[n * 256 + k] = f2bf(W[k * 256 + n]);
    }
  }
}

// ------------------------------- scan ----------------------------------------
__global__ __launch_bounds__(1024) void scan1_kernel(const int* __restrict__ deg,
                                                     int* __restrict__ row_start,
                                                     int* __restrict__ bsum, int N) {
  __shared__ int buf[1024];
  int i = blockIdx.x * 1024 + (int)threadIdx.x;
  int v = (i < N) ? deg[i] : 0;
  buf[threadIdx.x] = v;
  __syncthreads();
  int run = v;
  for (int off = 1; off < 1024; off <<= 1) {
    int t = ((int)threadIdx.x >= off) ? buf[threadIdx.x - off] : 0;
    __syncthreads();
    run += t;
    buf[threadIdx.x] = run;
    __syncthreads();
  }
  if (i < N) row_start[i] = run - v;  // exclusive, pre-block-offset
  if (threadIdx.x == 1023) bsum[blockIdx.x] = run;
}

__global__ __launch_bounds__(1024) void scan_off(int* __restrict__ row_start,
                                                 const int* __restrict__ bsum,
                                                 int nb, int N) {
  __shared__ int s_off;
  int b = blockIdx.x;
  if (threadIdx.x < 64) {
    int acc = 0;
    for (int j = (int)threadIdx.x; j < b; j += 64) acc += bsum[j];
    for (int off = 32; off; off >>= 1) acc += __shfl_down(acc, off, 64);
    if (threadIdx.x == 0) s_off = acc;
  }
  __syncthreads();
  int off = s_off;
  int i = b * 1024 + (int)threadIdx.x;
  if (i < N) row_start[i] += off;
  if (b == nb - 1 && threadIdx.x == 0) row_start[N] = off + bsum[b];
}

// ---- K4: MFMA GEMM (+fused att dots) || CSR fill ----------------------------
__global__ __launch_bounds__(256) void fused_main(
    const unsigned short* __restrict__ Xb, const unsigned short* __restrict__ Wtb,
    const float* __restrict__ attS, const float* __restrict__ attD,
    unsigned short* __restrict__ XHb, float* __restrict__ a_src,
    float* __restrict__ a_dst,
    const int* __restrict__ ei, const int* __restrict__ row_start,
    int* __restrict__ cursor, int* __restrict__ csr_src,
    int nGemm, int E, int N) {
  __shared__ unsigned short lA[128 * 32];
  __shared__ unsigned short lB[128 * 32];
  const int bid = blockIdx.x;
  const int tid = threadIdx.x;

  if (bid >= nGemm) {
    int bb = bid - nGemm;
    for (int e = bb * 256 + tid; e < E; e += CBF * 256) {
      int d = ei[E + e];
      int slot = row_start[d] + atomicAdd(&cursor[d], 1);
      csr_src[slot] = ei[e];
    }
    return;
  }

  const int lane = tid & 63;
  const int wave = tid >> 6;
  const int n0 = (bid & 1) * 128;
  const int m0 = (bid >> 1) * 128;
  const int wr = (wave >> 1) * 64;
  const int wc = (wave & 1) * 64;

  f32x4v acc[4][4];
#pragma unroll
  for (int i = 0; i < 4; ++i)
#pragma unroll
    for (int j = 0; j < 4; ++j) acc[i][j] = (f32x4v)(0.0f);

  const int srow = tid >> 2;
  const int skb = (tid & 3) * 16;
  const char* XbC = (const char*)Xb;
  const char* WtC = (const char*)Wtb;
  char* lAc = (char*)&lA[0];
  char* lBc = (char*)&lB[0];
  const int ldsB0 = wave * 1024;
  const int lr = lane & 15;
  const int hq = lane >> 4;
  const int kq = hq * 16;

  for (int k0 = 0; k0 < 256; k0 += 32) {
    const size_t kbyte = (size_t)k0 * 2 + skb;
    gload_lds16(XbC + (size_t)(m0 + srow) * 512 + kbyte, lAc + ldsB0);
    gload_lds16(XbC + (size_t)(m0 + srow + 64) * 512 + kbyte, lAc + ldsB0 + 4096);
    gload_lds16(WtC + (size_t)(n0 + srow) * 512 + kbyte, lBc + ldsB0);
    gload_lds16(WtC + (size_t)(n0 + srow + 64) * 512 + kbyte, lBc + ldsB0 + 4096);
    __syncthreads();

    short8 a[4], b[4];
#pragma unroll
    for (int i = 0; i < 4; ++i)
      a[i] = *reinterpret_cast<const short8*>(lAc + (wr + i * 16 + lr) * 64 + kq);
#pragma unroll
    for (int j = 0; j < 4; ++j)
      b[j] = *reinterpret_cast<const short8*>(lBc + (wc + j * 16 + lr) * 64 + kq);
#pragma unroll
    for (int i = 0; i < 4; ++i)
#pragma unroll
      for (int j = 0; j < 4; ++j)
        acc[i][j] = __builtin_amdgcn_mfma_f32_16x16x32_bf16(a[i], b[j], acc[i][j], 0, 0, 0);
    __syncthreads();
  }

  const int h = (n0 + wc) >> 6;
  float ws_[4], wd_[4];
#pragma unroll
  for (int j = 0; j < 4; ++j) {
    ws_[j] = attS[h * 64 + j * 16 + lr];
    wd_[j] = attD[h * 64 + j * 16 + lr];
  }
  const int rbase = m0 + wr + hq * 4;

#pragma unroll
  for (int i = 0; i < 4; ++i) {
#pragma unroll
    for (int r = 0; r < 4; ++r) {
      float ps = 0.f, pd = 0.f;
#pragma unroll
      for (int j = 0; j < 4; ++j) {
        ps += acc[i][j][r] * ws_[j];
        pd += acc[i][j][r] * wd_[j];
      }
#pragma unroll
      for (int off = 1; off < 16; off <<= 1) {
        ps += __shfl_xor(ps, off, 64);
        pd += __shfl_xor(pd, off, 64);
      }
      int row = rbase + i * 16 + r;
      if (lr == 0 && row < N) {
        a_src[row * 4 + h] = ps;
        a_dst[row * 4 + h] = pd;
      }
    }
  }

#pragma unroll
  for (int i = 0; i < 4; ++i)
#pragma unroll
    for (int j = 0; j < 4; ++j) {
      int col = n0 + wc + j * 16 + lr;
#pragma unroll
      for (int r = 0; r < 4; ++r)
        XHb[(size_t)(rbase + i * 16 + r) * 256 + col] = f2bf(acc[i][j][r]);
    }
}

// ---- fused softmax + aggregation, half-wave row gathers ---------------------
// one wave per dst node; each 32-lane half covers a full 512B row (16B/lane),
// halves process interleaved even/odd edges -> 1KB per load instruction.
__global__ __launch_bounds__(256) void gat_agg(
    const unsigned short* __restrict__ XHb, const float* __restrict__ a_src,
    const float* __restrict__ a_dst, const int* __restrict__ row_start,
    const int* __restrict__ csr_src, const float* __restrict__ bias,
    float* __restrict__ out, int N) {
  int wid = threadIdx.x >> 6;
  int lane = threadIdx.x & 63;
  int node = blockIdx.x * 4 + wid;
  if (node >= N) return;

  const int half = lane >> 5;
  const int l5 = lane & 31;
  const int h = l5 >> 3;   // head of this lane's 8-channel group
  const int c = l5 << 3;   // channel base (8 channels, 16B bf16)
  const unsigned short* __restrict__ xrow = XHb + c;

  float ad_h = a_dst[node * 4 + h];
  float as_h = a_src[node * 4 + h];

  int start = row_start[node];
  int end = row_start[node + 1];

  float acc[8];
  float sw = 0.f;
  if (half == 0) {
    float wself = __expf(LRELU(as_h + ad_h));
    ushort8 sv = *reinterpret_cast<const ushort8*>(xrow + (size_t)node * 256);
#pragma unroll
    for (int k = 0; k < 8; ++k) acc[k] = wself * bf2f(sv[k]);
    sw = wself;
  } else {
#pragma unroll
    for (int k = 0; k < 8; ++k) acc[k] = 0.f;
  }

  int p = start;
  for (; p + 8 <= end; p += 8) {
    int s0 = csr_src[p + half];
    int s1 = csr_src[p + 2 + half];
    int s2 = csr_src[p + 4 + half];
    int s3 = csr_src[p + 6 + half];
    float a0 = a_src[s0 * 4 + h] + ad_h;
    float a1 = a_src[s1 * 4 + h] + ad_h;
    float a2 = a_src[s2 * 4 + h] + ad_h;
    float a3 = a_src[s3 * 4 + h] + ad_h;
    ushort8 u0 = *reinterpret_cast<const ushort8*>(xrow + (size_t)s0 * 256);
    ushort8 u1 = *reinterpret_cast<const ushort8*>(xrow + (size_t)s1 * 256);
    ushort8 u2 = *reinterpret_cast<const ushort8*>(xrow + (size_t)s2 * 256);
    ushort8 u3 = *reinterpret_cast<const ushort8*>(xrow + (size_t)s3 * 256);
    float w0 = __expf(LRELU(a0));
    float w1 = __expf(LRELU(a1));
    float w2 = __expf(LRELU(a2));
    float w3 = __expf(LRELU(a3));
#pragma unroll
    for (int k = 0; k < 8; ++k) {
      acc[k] += w0 * bf2f(u0[k]);
      acc[k] += w1 * bf2f(u1[k]);
      acc[k] += w2 * bf2f(u2[k]);
      acc[k] += w3 * bf2f(u3[k]);
    }
    sw += (w0 + w1) + (w2 + w3);
  }
  // tail: up to 7 edges; idx uniform within each half
#pragma unroll
  for (int k = 0; k < 4; ++k) {
    int idx = p + 2 * k + half;
    if (idx < end) {
      int s = csr_src[idx];
      float aa = a_src[s * 4 + h] + ad_h;
      ushort8 u = *reinterpret_cast<const ushort8*>(xrow + (size_t)s * 256);
      float ww = __expf(LRELU(aa));
#pragma unroll
      for (int q = 0; q < 8; ++q) acc[q] += ww * bf2f(u[q]);
      sw += ww;
    }
  }

  // cross-half combine
  sw += __shfl_xor(sw, 32, 64);
#pragma unroll
  for (int k = 0; k < 8; ++k) acc[k] += __shfl_xor(acc[k], 32, 64);

  if (half == 0) {
    float inv = 1.0f / sw;
    float4 b0 = *reinterpret_cast<const float4*>(bias + c);
    float4 b1 = *reinterpret_cast<const float4*>(bias + c + 4);
    float4 o0, o1;
    o0.x = acc[0] * inv + b0.x; o0.y = acc[1] * inv + b0.y;
    o0.z = acc[2] * inv + b0.z; o0.w = acc[3] * inv + b0.w;
    o1.x = acc[4] * inv + b1.x; o1.y = acc[5] * inv + b1.y;
    o1.z = acc[6] * inv + b1.z; o1.w = acc[7] * inv + b1.w;
    *reinterpret_cast<float4*>(out + (size_t)node * 256 + c) = o0;
    *reinterpret_cast<float4*>(out + (size_t)node * 256 + c + 4) = o1;
  }
}

extern "C" void kernel_launch(void* const* d_in, const int* in_sizes, int n_in,
                              void* d_out, int out_size, void* d_ws, size_t ws_size,
                              hipStream_t stream) {
  const float* x    = (const float*)d_in[0];
  const int*   ei   = (const int*)d_in[1];
  const float* Wm   = (const float*)d_in[2];
  const float* attS = (const float*)d_in[3];
  const float* attD = (const float*)d_in[4];
  const float* bias = (const float*)d_in[5];
  float* out = (float*)d_out;

  const int N = in_sizes[0] / 256;
  const int E = in_sizes[1] / 2;
  const int Mp = (N + 127) / 128 * 128;
  const int nb = (N + 1023) / 1024;

  char* w = (char*)d_ws;
  unsigned short* XHb = (unsigned short*)w;  w += (size_t)Mp * 256 * 2;
  unsigned short* Xb  = (unsigned short*)w;  w += (size_t)Mp * 256 * 2;
  unsigned short* Wtb = (unsigned short*)w;  w += (size_t)256 * 256 * 2;
  float* a_src = (float*)w;                  w += (size_t)N * 4 * 4;
  float* a_dst = (float*)w;                  w += (size_t)N * 4 * 4;
  int* deg = (int*)w;                        w += (size_t)N * 4;
  int* cursor = (int*)w;                     w += (size_t)N * 4;
  int* row_start = (int*)w;                  w += ((size_t)(N + 1) * 4 + 255) / 256 * 256;
  int* bsum = (int*)w;                       w += ((size_t)nb * 4 + 255) / 256 * 256;
  int* csr_src = (int*)w;                    w += (size_t)E * 4;

  hipMemsetAsync(deg, 0, (size_t)2 * N * 4, stream);

  fused_pre<<<CBX + CBC + CBW, 256, 0, stream>>>(x, Xb, Wm, Wtb, ei, deg,
                                                 Mp * 256, N * 256, E);

  scan1_kernel<<<nb, 1024, 0, stream>>>(deg, row_start, bsum, N);
  scan_off<<<nb, 1024, 0, stream>>>(row_start, bsum, nb, N);

  const int nGemm = 2 * (Mp / 128);
  fused_main<<<nGemm + CBF, 256, 0, stream>>>(Xb, Wtb, attS, attD, XHb, a_src, a_dst,
                                              ei, row_start, cursor, csr_src,
                                              nGemm, E, N);

  gat_agg<<<(N + 3) / 4, 256, 0, stream>>>(XHb, a_src, a_dst, row_start, csr_src,
                                           bias, out, N);
}

// Round 8
// 167.222 us; speedup vs baseline: 1.2134x; 1.0362x over previous
//
#include <hip/hip_runtime.h>

#define NEG_SLOPE 0.2f
#define LRELU(x) ((x) > 0.0f ? (x) : NEG_SLOPE * (x))

typedef short short8 __attribute__((ext_vector_type(8)));
typedef unsigned short ushort8 __attribute__((ext_vector_type(8)));
typedef float f32x4v __attribute__((ext_vector_type(4)));

__device__ __forceinline__ unsigned short f2bf(float f) {
  unsigned int u = __float_as_uint(f);
  unsigned int r = (u + 0x7FFFu + ((u >> 16) & 1u)) >> 16;
  return (unsigned short)r;
}

__device__ __forceinline__ float bf2f(unsigned short u) {
  return __uint_as_float(((unsigned int)u) << 16);
}

__device__ __forceinline__ unsigned int cvt_pk_bf16(float lo, float hi) {
  unsigned int r;
  asm("v_cvt_pk_bf16_f32 %0, %1, %2" : "=v"(r) : "v"(lo), "v"(hi));
  return r;
}

__device__ __forceinline__ void gload_lds16(const void* g, void* l) {
  __builtin_amdgcn_global_load_lds(
      (const __attribute__((address_space(1))) unsigned int*)g,
      (__attribute__((address_space(3))) unsigned int*)l, 16, 0, 0);
}

// block-range split constants
#define CBC 448   // count blocks (fused_pre)
#define CBW 64    // convert_wt blocks (fused_pre)
#define CBF 512   // fill blocks (fused_main)

// ---- K1: count || convert_wt ------------------------------------------------
__global__ __launch_bounds__(256) void fused_pre(
    const float* __restrict__ W, unsigned short* __restrict__ Wtb,
    const int* __restrict__ ei, int* __restrict__ deg, int E) {
  int b = blockIdx.x;
  int tid = threadIdx.x;
  if (b < CBC) {
    for (int e = b * 256 + tid; e < E; e += CBC * 256)
      atomicAdd(&deg[ei[E + e]], 1);
  } else {
    int bb = b - CBC;
    for (int idx = bb * 256 + tid; idx < 256 * 256; idx += CBW * 256) {
      int n = idx >> 8, k = idx & 255;
      Wtb[n * 256 + k] = f2bf(W[k * 256 + n]);
    }
  }
}

// ------------------------------- scan ----------------------------------------
__global__ __launch_bounds__(1024) void scan1_kernel(const int* __restrict__ deg,
                                                     int* __restrict__ row_start,
                                                     int* __restrict__ bsum, int N) {
  __shared__ int buf[1024];
  int i = blockIdx.x * 1024 + (int)threadIdx.x;
  int v = (i < N) ? deg[i] : 0;
  buf[threadIdx.x] = v;
  __syncthreads();
  int run = v;
  for (int off = 1; off < 1024; off <<= 1) {
    int t = ((int)threadIdx.x >= off) ? buf[threadIdx.x - off] : 0;
    __syncthreads();
    run += t;
    buf[threadIdx.x] = run;
    __syncthreads();
  }
  if (i < N) row_start[i] = run - v;  // exclusive, pre-block-offset
  if (threadIdx.x == 1023) bsum[blockIdx.x] = run;
}

__global__ __launch_bounds__(1024) void scan_off(int* __restrict__ row_start,
                                                 const int* __restrict__ bsum,
                                                 int nb, int N) {
  __shared__ int s_off;
  int b = blockIdx.x;
  if (threadIdx.x < 64) {
    int acc = 0;
    for (int j = (int)threadIdx.x; j < b; j += 64) acc += bsum[j];
    for (int off = 32; off; off >>= 1) acc += __shfl_down(acc, off, 64);
    if (threadIdx.x == 0) s_off = acc;
  }
  __syncthreads();
  int off = s_off;
  int i = b * 1024 + (int)threadIdx.x;
  if (i < N) row_start[i] += off;
  if (b == nb - 1 && threadIdx.x == 0) row_start[N] = off + bsum[b];
}

// ---- K4: MFMA GEMM (full-N, fused x->bf16 + att dots) || CSR fill -----------
// BM=64, N=256 per block. A: reg-staged f32 -> cvt_pk -> bf16 LDS (convert_x
// pass eliminated; A read once total). B: gload_lds from Wtb (L2-resident).
// 4 waves: 2 row-groups x 2 col-groups; each wave 32 rows x 64 cols x 2 halves.
__global__ __launch_bounds__(256, 3) void fused_main(
    const float* __restrict__ Xf, const unsigned short* __restrict__ Wtb,
    const float* __restrict__ attS, const float* __restrict__ attD,
    unsigned short* __restrict__ XHb, float* __restrict__ a_src,
    float* __restrict__ a_dst,
    const int* __restrict__ ei, const int* __restrict__ row_start,
    int* __restrict__ cursor, int* __restrict__ csr_src,
    int nGemm, int E, int N) {
  __shared__ unsigned short lA[64 * 32];    // 4KB  [row][k], 64B/row
  __shared__ unsigned short lB[256 * 32];   // 16KB [n][k],   64B/row
  const int bid = blockIdx.x;
  const int tid = threadIdx.x;

  if (bid >= nGemm) {
    // ---------------- fill ----------------
    int bb = bid - nGemm;
    for (int e = bb * 256 + tid; e < E; e += CBF * 256) {
      int d = ei[E + e];
      int slot = row_start[d] + atomicAdd(&cursor[d], 1);
      csr_src[slot] = ei[e];
    }
    return;
  }

  // ---------------- gemm ----------------
  const int lane = tid & 63;
  const int wave = tid >> 6;
  const int m0 = bid * 64;
  const int wrow = (wave >> 1) * 32;  // wave row group within 64-row tile
  const int wc = (wave & 1) * 64;     // wave col group within each 128-half

  f32x4v acc[2][8];  // [i][half*4+j]
#pragma unroll
  for (int i = 0; i < 2; ++i)
#pragma unroll
    for (int j = 0; j < 8; ++j) acc[i][j] = (f32x4v)(0.0f);

  // B staging: 4 issues x 4KB; issue is covers n-rows [is*64, is*64+64)
  const int srow = tid >> 2;
  const int skb = (tid & 3) * 16;
  // A reg staging: 64 rows x 128B(f32, BK=32) -> 32B/thread
  const int arow = tid >> 2;          // 0..63
  const int acol = (tid & 3) * 8;     // float offset within 32-float chunk
  const float* aptr = Xf + (size_t)min(m0 + arow, N - 1) * 256 + acol;

  const char* WtC = (const char*)Wtb;
  char* lAc = (char*)&lA[0];
  char* lBc = (char*)&lB[0];
  const int ldsW = wave * 1024;
  const int lr = lane & 15;
  const int hq = lane >> 4;

  // prologue: A regs for k0 = 0
  float4 nv0 = *reinterpret_cast<const float4*>(aptr);
  float4 nv1 = *reinterpret_cast<const float4*>(aptr + 4);

#pragma unroll
  for (int kk = 0; kk < 8; ++kk) {
    const int k0 = kk * 32;
    // B: 4 gload_lds issues (wave-uniform dest + lane*16)
#pragma unroll
    for (int is = 0; is < 4; ++is)
      gload_lds16(WtC + (size_t)(is * 64 + srow) * 512 + (size_t)k0 * 2 + skb,
                  lBc + is * 4096 + ldsW);
    // A: cvt current regs -> bf16, write LDS
    {
      uint4 wv;
      wv.x = cvt_pk_bf16(nv0.x, nv0.y);
      wv.y = cvt_pk_bf16(nv0.z, nv0.w);
      wv.z = cvt_pk_bf16(nv1.x, nv1.y);
      wv.w = cvt_pk_bf16(nv1.z, nv1.w);
      *reinterpret_cast<uint4*>(lAc + arow * 64 + (tid & 3) * 16) = wv;
    }
    // prefetch next A chunk
    if (kk < 7) {
      nv0 = *reinterpret_cast<const float4*>(aptr + k0 + 32);
      nv1 = *reinterpret_cast<const float4*>(aptr + k0 + 36);
    }
    __syncthreads();

    short8 a[2];
#pragma unroll
    for (int i = 0; i < 2; ++i)
      a[i] = *reinterpret_cast<const short8*>(lAc + (wrow + i * 16 + lr) * 64 + hq * 16);
#pragma unroll
    for (int half = 0; half < 2; ++half) {
      short8 b[4];
#pragma unroll
      for (int j = 0; j < 4; ++j)
        b[j] = *reinterpret_cast<const short8*>(
            lBc + (half * 128 + wc + j * 16 + lr) * 64 + hq * 16);
#pragma unroll
      for (int i = 0; i < 2; ++i)
#pragma unroll
        for (int j = 0; j < 4; ++j)
          acc[i][half * 4 + j] =
              __builtin_amdgcn_mfma_f32_16x16x32_bf16(a[i], b[j], acc[i][half * 4 + j], 0, 0, 0);
    }
    __syncthreads();
  }

  // ---- epilogue: fused attention dots + bf16 store, per half ----
  const int rbase = m0 + wrow + hq * 4;
#pragma unroll
  for (int half = 0; half < 2; ++half) {
    const int h = half * 2 + (wave & 1);  // head of this wave's 64-col span
    float ws_[4], wd_[4];
#pragma unroll
    for (int j = 0; j < 4; ++j) {
      ws_[j] = attS[h * 64 + j * 16 + lr];
      wd_[j] = attD[h * 64 + j * 16 + lr];
    }
#pragma unroll
    for (int i = 0; i < 2; ++i) {
#pragma unroll
      for (int r = 0; r < 4; ++r) {
        float ps = 0.f, pd = 0.f;
#pragma unroll
        for (int j = 0; j < 4; ++j) {
          ps += acc[i][half * 4 + j][r] * ws_[j];
          pd += acc[i][half * 4 + j][r] * wd_[j];
        }
#pragma unroll
        for (int off = 1; off < 16; off <<= 1) {
          ps += __shfl_xor(ps, off, 64);
          pd += __shfl_xor(pd, off, 64);
        }
        int row = rbase + i * 16 + r;
        if (lr == 0 && row < N) {
          a_src[row * 4 + h] = ps;
          a_dst[row * 4 + h] = pd;
        }
      }
    }
#pragma unroll
    for (int i = 0; i < 2; ++i)
#pragma unroll
      for (int j = 0; j < 4; ++j) {
        int col = half * 128 + wc + j * 16 + lr;
#pragma unroll
        for (int r = 0; r < 4; ++r)
          XHb[(size_t)(rbase + i * 16 + r) * 256 + col] = f2bf(acc[i][half * 4 + j][r]);
      }
  }
}

// ---- fused softmax + aggregation, half-wave row gathers (R7-best) -----------
__global__ __launch_bounds__(256) void gat_agg(
    const unsigned short* __restrict__ XHb, const float* __restrict__ a_src,
    const float* __restrict__ a_dst, const int* __restrict__ row_start,
    const int* __restrict__ csr_src, const float* __restrict__ bias,
    float* __restrict__ out, int N) {
  int wid = threadIdx.x >> 6;
  int lane = threadIdx.x & 63;
  int node = blockIdx.x * 4 + wid;
  if (node >= N) return;

  const int half = lane >> 5;
  const int l5 = lane & 31;
  const int h = l5 >> 3;
  const int c = l5 << 3;
  const unsigned short* __restrict__ xrow = XHb + c;

  float ad_h = a_dst[node * 4 + h];
  float as_h = a_src[node * 4 + h];

  int start = row_start[node];
  int end = row_start[node + 1];

  float acc[8];
  float sw = 0.f;
  if (half == 0) {
    float wself = __expf(LRELU(as_h + ad_h));
    ushort8 sv = *reinterpret_cast<const ushort8*>(xrow + (size_t)node * 256);
#pragma unroll
    for (int k = 0; k < 8; ++k) acc[k] = wself * bf2f(sv[k]);
    sw = wself;
  } else {
#pragma unroll
    for (int k = 0; k < 8; ++k) acc[k] = 0.f;
  }

  int p = start;
  for (; p + 8 <= end; p += 8) {
    int s0 = csr_src[p + half];
    int s1 = csr_src[p + 2 + half];
    int s2 = csr_src[p + 4 + half];
    int s3 = csr_src[p + 6 + half];
    float a0 = a_src[s0 * 4 + h] + ad_h;
    float a1 = a_src[s1 * 4 + h] + ad_h;
    float a2 = a_src[s2 * 4 + h] + ad_h;
    float a3 = a_src[s3 * 4 + h] + ad_h;
    ushort8 u0 = *reinterpret_cast<const ushort8*>(xrow + (size_t)s0 * 256);
    ushort8 u1 = *reinterpret_cast<const ushort8*>(xrow + (size_t)s1 * 256);
    ushort8 u2 = *reinterpret_cast<const ushort8*>(xrow + (size_t)s2 * 256);
    ushort8 u3 = *reinterpret_cast<const ushort8*>(xrow + (size_t)s3 * 256);
    float w0 = __expf(LRELU(a0));
    float w1 = __expf(LRELU(a1));
    float w2 = __expf(LRELU(a2));
    float w3 = __expf(LRELU(a3));
#pragma unroll
    for (int k = 0; k < 8; ++k) {
      acc[k] += w0 * bf2f(u0[k]);
      acc[k] += w1 * bf2f(u1[k]);
      acc[k] += w2 * bf2f(u2[k]);
      acc[k] += w3 * bf2f(u3[k]);
    }
    sw += (w0 + w1) + (w2 + w3);
  }
#pragma unroll
  for (int k = 0; k < 4; ++k) {
    int idx = p + 2 * k + half;
    if (idx < end) {
      int s = csr_src[idx];
      float aa = a_src[s * 4 + h] + ad_h;
      ushort8 u = *reinterpret_cast<const ushort8*>(xrow + (size_t)s * 256);
      float ww = __expf(LRELU(aa));
#pragma unroll
      for (int q = 0; q < 8; ++q) acc[q] += ww * bf2f(u[q]);
      sw += ww;
    }
  }

  sw += __shfl_xor(sw, 32, 64);
#pragma unroll
  for (int k = 0; k < 8; ++k) acc[k] += __shfl_xor(acc[k], 32, 64);

  if (half == 0) {
    float inv = 1.0f / sw;
    float4 b0 = *reinterpret_cast<const float4*>(bias + c);
    float4 b1 = *reinterpret_cast<const float4*>(bias + c + 4);
    float4 o0, o1;
    o0.x = acc[0] * inv + b0.x; o0.y = acc[1] * inv + b0.y;
    o0.z = acc[2] * inv + b0.z; o0.w = acc[3] * inv + b0.w;
    o1.x = acc[4] * inv + b1.x; o1.y = acc[5] * inv + b1.y;
    o1.z = acc[6] * inv + b1.z; o1.w = acc[7] * inv + b1.w;
    *reinterpret_cast<float4*>(out + (size_t)node * 256 + c) = o0;
    *reinterpret_cast<float4*>(out + (size_t)node * 256 + c + 4) = o1;
  }
}

extern "C" void kernel_launch(void* const* d_in, const int* in_sizes, int n_in,
                              void* d_out, int out_size, void* d_ws, size_t ws_size,
                              hipStream_t stream) {
  const float* x    = (const float*)d_in[0];
  const int*   ei   = (const int*)d_in[1];
  const float* Wm   = (const float*)d_in[2];
  const float* attS = (const float*)d_in[3];
  const float* attD = (const float*)d_in[4];
  const float* bias = (const float*)d_in[5];
  float* out = (float*)d_out;

  const int N = in_sizes[0] / 256;
  const int E = in_sizes[1] / 2;
  const int Mp = (N + 63) / 64 * 64;
  const int nb = (N + 1023) / 1024;

  char* w = (char*)d_ws;
  unsigned short* XHb = (unsigned short*)w;  w += (size_t)Mp * 256 * 2;
  unsigned short* Wtb = (unsigned short*)w;  w += (size_t)256 * 256 * 2;
  float* a_src = (float*)w;                  w += (size_t)N * 4 * 4;
  float* a_dst = (float*)w;                  w += (size_t)N * 4 * 4;
  int* deg = (int*)w;                        w += (size_t)N * 4;
  int* cursor = (int*)w;                     w += (size_t)N * 4;
  int* row_start = (int*)w;                  w += ((size_t)(N + 1) * 4 + 255) / 256 * 256;
  int* bsum = (int*)w;                       w += ((size_t)nb * 4 + 255) / 256 * 256;
  int* csr_src = (int*)w;                    w += (size_t)E * 4;

  hipMemsetAsync(deg, 0, (size_t)2 * N * 4, stream);  // deg + cursor (adjacent)

  fused_pre<<<CBC + CBW, 256, 0, stream>>>(Wm, Wtb, ei, deg, E);

  scan1_kernel<<<nb, 1024, 0, stream>>>(deg, row_start, bsum, N);
  scan_off<<<nb, 1024, 0, stream>>>(row_start, bsum, nb, N);

  const int nGemm = Mp / 64;
  fused_main<<<nGemm + CBF, 256, 0, stream>>>(x, Wtb, attS, attD, XHb, a_src, a_dst,
                                              ei, row_start, cursor, csr_src,
                                              nGemm, E, N);

  gat_agg<<<(N + 3) / 4, 256, 0, stream>>>(XHb, a_src, a_dst, row_start, csr_src,
                                           bias, out, N);
}